// Round 1
// baseline (3505.214 us; speedup 1.0000x reference)
//
#include <hip/hip_runtime.h>
#include <hip/hip_bf16.h>

#define N_NODES 100000
#define N_EDGES 1600000
#define N_GRAPHS 250

__device__ __forceinline__ void atomAddF(float* p, float v) {
  // hardware global_atomic_add_f32 (device scope); avoids CAS-loop fallback
  unsafeAtomicAdd(p, v);
}

// Build x0 [N,16]: [node_h(9) | xg[batch](4) | 0,0,0]
__global__ void concat_kernel(const float* __restrict__ nh, const float* __restrict__ xg,
                              const int* __restrict__ batch, float* __restrict__ x0) {
  int idx = blockIdx.x * blockDim.x + threadIdx.x;
  if (idx >= N_NODES * 16) return;
  int n = idx >> 4, j = idx & 15;
  float v;
  if (j < 9)       v = nh[n * 9 + j];
  else if (j < 13) v = xg[batch[n] * 4 + (j - 9)];
  else             v = 0.0f;
  x0[idx] = v;
}

__global__ void deg_kernel(const int* __restrict__ dst, float* __restrict__ deg) {
  int e = blockIdx.x * blockDim.x + threadIdx.x;
  if (e >= N_EDGES) return;
  atomAddF(&deg[dst[e]], 1.0f);
}

__global__ void inv_kernel(const float* __restrict__ deg, float* __restrict__ inv) {
  int n = blockIdx.x * blockDim.x + threadIdx.x;
  if (n >= N_NODES) return;
  inv[n] = 1.0f / fmaxf(deg[n], 1.0f);
}

// scatter-add aggregation: agg[dst] += x[src]; F/4 threads per edge, float4 loads
template <int F>
__global__ void agg_kernel(const float* __restrict__ x, const int* __restrict__ src,
                           const int* __restrict__ dst, float* __restrict__ agg) {
  constexpr int TPE = F / 4;  // power of two
  long idx = (long)blockIdx.x * blockDim.x + threadIdx.x;
  const long total = (long)N_EDGES * TPE;
  if (idx >= total) return;
  int e = (int)(idx / TPE);
  int j = (int)(idx % TPE);
  int s = src[e], d = dst[e];
  const float4 v = *(const float4*)(x + (size_t)s * F + j * 4);
  float* a = agg + (size_t)d * F + j * 4;
  atomAddF(a + 0, v.x);
  atomAddF(a + 1, v.y);
  atomAddF(a + 2, v.z);
  atomAddF(a + 3, v.w);
}

// out[n][h] = (relu?)( (agg[n]/deg[n]) . Wl[h] + bl[h] + x[n] . Wr[h] )
// 256 threads = 4 nodes x 64 h-lanes; W transposed in LDS (bank = h%32, conflict-free)
template <int F, bool RELU>
__global__ void sage_kernel(const float* __restrict__ x, const float* __restrict__ agg,
                            const float* __restrict__ inv, const float* __restrict__ Wl,
                            const float* __restrict__ bl, const float* __restrict__ Wr,
                            int Fw, float* __restrict__ out) {
  __shared__ float Wlt[F * 64];
  __shared__ float Wrt[F * 64];
  __shared__ float xs[4][F];
  __shared__ float as[4][F];
  for (int i = threadIdx.x; i < 64 * F; i += blockDim.x) {
    int h = i / F, f = i % F;
    Wlt[f * 64 + h] = (f < Fw) ? Wl[h * Fw + f] : 0.0f;
    Wrt[f * 64 + h] = (f < Fw) ? Wr[h * Fw + f] : 0.0f;
  }
  __syncthreads();
  const int h = threadIdx.x & 63;
  const int i = threadIdx.x >> 6;
  const float blv = bl[h];
  const int ntiles = N_NODES / 4;  // N divisible by 4
  for (int t = blockIdx.x; t < ntiles; t += gridDim.x) {
    int n = t * 4 + i;
    if (h < F) {
      xs[i][h] = x[(size_t)n * F + h];
      as[i][h] = agg[(size_t)n * F + h] * inv[n];
    }
    __syncthreads();
    float acc = blv;
#pragma unroll
    for (int f = 0; f < F; ++f)
      acc = fmaf(as[i][f], Wlt[f * 64 + h], fmaf(xs[i][f], Wrt[f * 64 + h], acc));
    if (RELU) acc = fmaxf(acc, 0.0f);
    out[(size_t)n * 64 + h] = acc;
    __syncthreads();
  }
}

// scatter-mean pooling: batch_idx sorted -> run-detection, one atomic per run per wave
__global__ void pool_kernel(const float* __restrict__ x, const int* __restrict__ batch,
                            float* __restrict__ pooled, float* __restrict__ cnt) {
  int wave = (blockIdx.x * blockDim.x + threadIdx.x) >> 6;
  int lane = threadIdx.x & 63;
  int n0 = wave * 64;
  if (n0 >= N_NODES) return;
  int nend = n0 + 64 < N_NODES ? n0 + 64 : N_NODES;
  int cur = -1;
  float acc = 0.0f, run = 0.0f;
  for (int n = n0; n < nend; ++n) {
    int b = batch[n];  // wave-uniform
    float v = x[(size_t)n * 64 + lane];
    if (b != cur) {
      if (cur >= 0) {
        atomAddF(&pooled[cur * 64 + lane], acc);
        if (lane == 0) atomAddF(&cnt[cur], run);
      }
      cur = b; acc = v; run = 1.0f;
    } else {
      acc += v; run += 1.0f;
    }
  }
  if (cur >= 0) {
    atomAddF(&pooled[cur * 64 + lane], acc);
    if (lane == 0) atomAddF(&cnt[cur], run);
  }
}

// per-graph MLP 64->64->64->64->1; one 64-thread block per graph
__global__ void mlp_kernel(const float* __restrict__ pooled, const float* __restrict__ cnt,
                           const float* __restrict__ W0, const float* __restrict__ b0,
                           const float* __restrict__ W1, const float* __restrict__ b1,
                           const float* __restrict__ W2, const float* __restrict__ b2,
                           const float* __restrict__ W3, const float* __restrict__ b3,
                           float* __restrict__ out) {
  int g = blockIdx.x, t = threadIdx.x;  // 64 threads = 1 wave
  __shared__ float buf[2][64];
  float ic = 1.0f / fmaxf(cnt[g], 1.0f);
  buf[0][t] = pooled[g * 64 + t] * ic;
  __syncthreads();
  const float* Ws[3] = {W0, W1, W2};
  const float* Bs[3] = {b0, b1, b2};
  int cur = 0;
  for (int L = 0; L < 3; ++L) {
    const float* W = Ws[L];
    float acc = Bs[L][t];
#pragma unroll
    for (int f = 0; f < 64; ++f) acc = fmaf(W[t * 64 + f], buf[cur][f], acc);
    buf[cur ^ 1][t] = fmaxf(acc, 0.0f);
    __syncthreads();
    cur ^= 1;
  }
  float v = W3[t] * buf[cur][t];
  for (int off = 32; off; off >>= 1) v += __shfl_down(v, off);
  if (t == 0) out[g] = v + b3[0];
}

extern "C" void kernel_launch(void* const* d_in, const int* in_sizes, int n_in,
                              void* d_out, int out_size, void* d_ws, size_t ws_size,
                              hipStream_t stream) {
  const float* nh    = (const float*)d_in[0];
  const float* xg    = (const float*)d_in[1];
  const int*   ei    = (const int*)d_in[2];
  const int*   batch = (const int*)d_in[3];
  const float* s0Wl  = (const float*)d_in[4];
  const float* s0bl  = (const float*)d_in[5];
  const float* s0Wr  = (const float*)d_in[6];
  const float* s1Wl  = (const float*)d_in[7];
  const float* s1bl  = (const float*)d_in[8];
  const float* s1Wr  = (const float*)d_in[9];
  const float* s2Wl  = (const float*)d_in[10];
  const float* s2bl  = (const float*)d_in[11];
  const float* s2Wr  = (const float*)d_in[12];
  const float* mW0   = (const float*)d_in[13];
  const float* mb0   = (const float*)d_in[14];
  const float* mW1   = (const float*)d_in[15];
  const float* mb1   = (const float*)d_in[16];
  const float* mW2   = (const float*)d_in[17];
  const float* mb2   = (const float*)d_in[18];
  const float* mW3   = (const float*)d_in[19];
  const float* mb3   = (const float*)d_in[20];

  const int* src = ei;
  const int* dst = ei + N_EDGES;

  float* B0     = (float*)d_ws;                 // N*64
  float* B1     = B0 + (size_t)N_NODES * 64;    // N*64
  float* B2     = B1 + (size_t)N_NODES * 64;    // N*64
  float* deg    = B2 + (size_t)N_NODES * 64;    // N
  float* inv    = deg + N_NODES;                // N
  float* pooled = inv + N_NODES;                // 250*64
  float* cnt    = pooled + (size_t)N_GRAPHS * 64;  // 250

  // zero accumulators (ws is poisoned before every call)
  hipMemsetAsync(deg, 0, N_NODES * sizeof(float), stream);
  hipMemsetAsync(pooled, 0, (N_GRAPHS * 64 + N_GRAPHS) * sizeof(float), stream);
  hipMemsetAsync(B1, 0, (size_t)N_NODES * 16 * sizeof(float), stream);  // agg0 region

  concat_kernel<<<(N_NODES * 16 + 255) / 256, 256, 0, stream>>>(nh, xg, batch, B0);
  deg_kernel<<<(N_EDGES + 255) / 256, 256, 0, stream>>>(dst, deg);
  inv_kernel<<<(N_NODES + 255) / 256, 256, 0, stream>>>(deg, inv);

  // layer 0: x0=B0 (stride 16), agg0=B1 -> x1=B2
  agg_kernel<16><<<(int)(((long)N_EDGES * 4 + 255) / 256), 256, 0, stream>>>(B0, src, dst, B1);
  sage_kernel<16, true><<<2048, 256, 0, stream>>>(B0, B1, inv, s0Wl, s0bl, s0Wr, 13, B2);

  // layer 1: x1=B2, agg1=B0 -> x2=B1
  hipMemsetAsync(B0, 0, (size_t)N_NODES * 64 * sizeof(float), stream);
  agg_kernel<64><<<(int)(((long)N_EDGES * 16 + 255) / 256), 256, 0, stream>>>(B2, src, dst, B0);
  sage_kernel<64, true><<<2048, 256, 0, stream>>>(B2, B0, inv, s1Wl, s1bl, s1Wr, 64, B1);

  // layer 2: x2=B1, agg2=B2 -> x3=B0
  hipMemsetAsync(B2, 0, (size_t)N_NODES * 64 * sizeof(float), stream);
  agg_kernel<64><<<(int)(((long)N_EDGES * 16 + 255) / 256), 256, 0, stream>>>(B1, src, dst, B2);
  sage_kernel<64, false><<<2048, 256, 0, stream>>>(B1, B2, inv, s2Wl, s2bl, s2Wr, 64, B0);

  // pooling + MLP
  pool_kernel<<<((N_NODES + 63) / 64 * 64 + 255) / 256, 256, 0, stream>>>(B0, batch, pooled, cnt);
  mlp_kernel<<<N_GRAPHS, 64, 0, stream>>>(pooled, cnt, mW0, mb0, mW1, mb1, mW2, mb2, mW3, mb3,
                                          (float*)d_out);
}

// Round 3
// 1216.591 us; speedup vs baseline: 2.8812x; 2.8812x over previous
//
#include <hip/hip_runtime.h>
#include <hip/hip_bf16.h>

#define N_NODES 100000
#define N_EDGES 1600000
#define N_GRAPHS 250

__device__ __forceinline__ void atomAddF(float* p, float v) {
  unsafeAtomicAdd(p, v);  // hardware global_atomic_add_f32
}

// Build x0 [N,16]: [node_h(9) | xg[batch](4) | 0,0,0]
__global__ void concat_kernel(const float* __restrict__ nh, const float* __restrict__ xg,
                              const int* __restrict__ batch, float* __restrict__ x0) {
  int idx = blockIdx.x * blockDim.x + threadIdx.x;
  if (idx >= N_NODES * 16) return;
  int n = idx >> 4, j = idx & 15;
  float v;
  if (j < 9)       v = nh[n * 9 + j];
  else if (j < 13) v = xg[batch[n] * 4 + (j - 9)];
  else             v = 0.0f;
  x0[idx] = v;
}

// ---- CSR build: histogram -> scan -> scatter (int atomics only) ----
__global__ void hist_kernel(const int* __restrict__ dst, int* __restrict__ deg) {
  int e = blockIdx.x * blockDim.x + threadIdx.x;
  if (e < N_EDGES) atomicAdd(&deg[dst[e]], 1);
}

__global__ void inv_kernel(const int* __restrict__ deg, float* __restrict__ inv) {
  int n = blockIdx.x * blockDim.x + threadIdx.x;
  if (n < N_NODES) inv[n] = 1.0f / fmaxf((float)deg[n], 1.0f);
}

// single-block exclusive scan of deg -> rowptr (and cursor copy)
__global__ __launch_bounds__(1024) void scan_kernel(const int* __restrict__ deg,
                                                    int* __restrict__ rowptr,
                                                    int* __restrict__ cursor) {
  const int T = 1024;
  const int C = (N_NODES + T - 1) / T;  // 98
  __shared__ int part[T];
  int t = threadIdx.x;
  int lo = t * C, hi = lo + C < N_NODES ? lo + C : N_NODES;
  int s = 0;
  for (int i = lo; i < hi; ++i) s += deg[i];
  part[t] = s;
  __syncthreads();
  for (int off = 1; off < T; off <<= 1) {  // Hillis-Steele inclusive
    int add = (t >= off) ? part[t - off] : 0;
    __syncthreads();
    part[t] += add;
    __syncthreads();
  }
  int pre = (t == 0) ? 0 : part[t - 1];
  for (int i = lo; i < hi; ++i) {
    rowptr[i] = pre; cursor[i] = pre;
    pre += deg[i];
  }
  if (t == T - 1) rowptr[N_NODES] = N_EDGES;
}

__global__ void scatter_kernel(const int* __restrict__ src, const int* __restrict__ dst,
                               int* __restrict__ cursor, int* __restrict__ esorted) {
  int e = blockIdx.x * blockDim.x + threadIdx.x;
  if (e < N_EDGES) {
    int pos = atomicAdd(&cursor[dst[e]], 1);
    esorted[pos] = src[e];
  }
}

// ---- fused gather-mean-aggregate + SAGE transform ----
// block = 256 = 4 waves; each wave owns one node per tile.
// stage1: CSR gather of x[src] rows, accumulate in registers (lane=f), scale by 1/deg.
// stage2: out[n][h] = (relu?)(as.Wl[h] + bl[h] + xs.Wr[h]); weights transposed in LDS.
template <int F, bool RELU>
__launch_bounds__(256)
__global__ void sage_fused(const float* __restrict__ x, const int* __restrict__ rowptr,
                           const int* __restrict__ esorted, const float* __restrict__ inv,
                           const float* __restrict__ Wl, const float* __restrict__ bl,
                           const float* __restrict__ Wr, int Fw, float* __restrict__ out) {
  __shared__ float Wlt[F * 64];
  __shared__ float Wrt[F * 64];
  __shared__ float xs[4][F];
  __shared__ float as[4][F];
  for (int i = threadIdx.x; i < 64 * F; i += 256) {
    int h = i / F, f = i % F;
    Wlt[f * 64 + h] = (f < Fw) ? Wl[h * Fw + f] : 0.0f;
    Wrt[f * 64 + h] = (f < Fw) ? Wr[h * Fw + f] : 0.0f;
  }
  __syncthreads();
  const int lane = threadIdx.x & 63;
  const int w = threadIdx.x >> 6;
  const float blv = bl[lane];
  const int ntiles = N_NODES / 4;  // 25000
  for (int tile = blockIdx.x; tile < ntiles; tile += gridDim.x) {
    const int n = tile * 4 + w;
    const int e0 = rowptr[n], e1 = rowptr[n + 1];
    if (F == 64) {
      float acc = 0.0f;
      for (int e = e0; e < e1; ++e) {
        int s = esorted[e];  // wave-uniform broadcast
        acc += x[(size_t)s * 64 + lane];
      }
      as[w][lane] = acc * inv[n];
      xs[w][lane] = x[(size_t)n * 64 + lane];
    } else {  // F == 16: 4 edge-groups x 16 f-lanes
      const int g = lane >> 4, f = lane & 15;
      float acc = 0.0f;
      for (int e = e0 + g; e < e1; e += 4) {
        int s = esorted[e];
        acc += x[(size_t)s * 16 + f];
      }
      acc += __shfl_xor(acc, 16);
      acc += __shfl_xor(acc, 32);
      if (g == 0) {
        as[w][f] = acc * inv[n];
        xs[w][f] = x[(size_t)n * 16 + f];
      }
    }
    // wave-local LDS produce->consume: per-wave DS ops are in order; pin compiler order.
    __builtin_amdgcn_wave_barrier();
    float acc2 = blv;
#pragma unroll
    for (int f = 0; f < F; ++f)
      acc2 = fmaf(as[w][f], Wlt[f * 64 + lane], fmaf(xs[w][f], Wrt[f * 64 + lane], acc2));
    if (RELU) acc2 = fmaxf(acc2, 0.0f);
    out[(size_t)n * 64 + lane] = acc2;
    __builtin_amdgcn_wave_barrier();
  }
}

// scatter-mean pooling: batch_idx sorted -> run-detection, one atomic per run per wave
__global__ void pool_kernel(const float* __restrict__ x, const int* __restrict__ batch,
                            float* __restrict__ pooled, float* __restrict__ cnt) {
  int wave = (blockIdx.x * blockDim.x + threadIdx.x) >> 6;
  int lane = threadIdx.x & 63;
  int n0 = wave * 64;
  if (n0 >= N_NODES) return;
  int nend = n0 + 64 < N_NODES ? n0 + 64 : N_NODES;
  int cur = -1;
  float acc = 0.0f, run = 0.0f;
  for (int n = n0; n < nend; ++n) {
    int b = batch[n];  // wave-uniform
    float v = x[(size_t)n * 64 + lane];
    if (b != cur) {
      if (cur >= 0) {
        atomAddF(&pooled[cur * 64 + lane], acc);
        if (lane == 0) atomAddF(&cnt[cur], run);
      }
      cur = b; acc = v; run = 1.0f;
    } else {
      acc += v; run += 1.0f;
    }
  }
  if (cur >= 0) {
    atomAddF(&pooled[cur * 64 + lane], acc);
    if (lane == 0) atomAddF(&cnt[cur], run);
  }
}

// per-graph MLP 64->64->64->64->1; one 64-thread block per graph
__global__ void mlp_kernel(const float* __restrict__ pooled, const float* __restrict__ cnt,
                           const float* __restrict__ W0, const float* __restrict__ b0,
                           const float* __restrict__ W1, const float* __restrict__ b1,
                           const float* __restrict__ W2, const float* __restrict__ b2,
                           const float* __restrict__ W3, const float* __restrict__ b3,
                           float* __restrict__ out) {
  int g = blockIdx.x, t = threadIdx.x;
  __shared__ float buf[2][64];
  float ic = 1.0f / fmaxf(cnt[g], 1.0f);
  buf[0][t] = pooled[g * 64 + t] * ic;
  __syncthreads();
  const float* Ws[3] = {W0, W1, W2};
  const float* Bs[3] = {b0, b1, b2};
  int cur = 0;
  for (int L = 0; L < 3; ++L) {
    const float* W = Ws[L];
    float acc = Bs[L][t];
#pragma unroll
    for (int f = 0; f < 64; ++f) acc = fmaf(W[t * 64 + f], buf[cur][f], acc);
    buf[cur ^ 1][t] = fmaxf(acc, 0.0f);
    __syncthreads();
    cur ^= 1;
  }
  float v = W3[t] * buf[cur][t];
  for (int off = 32; off; off >>= 1) v += __shfl_down(v, off);
  if (t == 0) out[g] = v + b3[0];
}

extern "C" void kernel_launch(void* const* d_in, const int* in_sizes, int n_in,
                              void* d_out, int out_size, void* d_ws, size_t ws_size,
                              hipStream_t stream) {
  const float* nh    = (const float*)d_in[0];
  const float* xg    = (const float*)d_in[1];
  const int*   ei    = (const int*)d_in[2];
  const int*   batch = (const int*)d_in[3];
  const float* s0Wl  = (const float*)d_in[4];
  const float* s0bl  = (const float*)d_in[5];
  const float* s0Wr  = (const float*)d_in[6];
  const float* s1Wl  = (const float*)d_in[7];
  const float* s1bl  = (const float*)d_in[8];
  const float* s1Wr  = (const float*)d_in[9];
  const float* s2Wl  = (const float*)d_in[10];
  const float* s2bl  = (const float*)d_in[11];
  const float* s2Wr  = (const float*)d_in[12];
  const float* mW0   = (const float*)d_in[13];
  const float* mb0   = (const float*)d_in[14];
  const float* mW1   = (const float*)d_in[15];
  const float* mb1   = (const float*)d_in[16];
  const float* mW2   = (const float*)d_in[17];
  const float* mb2   = (const float*)d_in[18];
  const float* mW3   = (const float*)d_in[19];
  const float* mb3   = (const float*)d_in[20];

  const int* src = ei;
  const int* dst = ei + N_EDGES;

  // ws layout
  float* B0     = (float*)d_ws;                     // N*64
  float* B1     = B0 + (size_t)N_NODES * 64;        // N*64
  float* inv    = B1 + (size_t)N_NODES * 64;        // N
  float* pooled = inv + N_NODES;                    // 250*64
  float* cnt    = pooled + (size_t)N_GRAPHS * 64;   // 250
  int*   deg     = (int*)(cnt + N_GRAPHS);          // N
  int*   rowptr  = deg + N_NODES;                   // N+1
  int*   cursor  = rowptr + (N_NODES + 1);          // N
  int*   esorted = cursor + N_NODES;                // E

  hipMemsetAsync(deg, 0, N_NODES * sizeof(int), stream);
  hipMemsetAsync(pooled, 0, (N_GRAPHS * 64 + N_GRAPHS) * sizeof(float), stream);

  // CSR build
  hist_kernel<<<(N_EDGES + 255) / 256, 256, 0, stream>>>(dst, deg);
  inv_kernel<<<(N_NODES + 255) / 256, 256, 0, stream>>>(deg, inv);
  scan_kernel<<<1, 1024, 0, stream>>>(deg, rowptr, cursor);
  scatter_kernel<<<(N_EDGES + 255) / 256, 256, 0, stream>>>(src, dst, cursor, esorted);

  // x0 (stride 16) into B0
  concat_kernel<<<(N_NODES * 16 + 255) / 256, 256, 0, stream>>>(nh, xg, batch, B0);

  // fused layers: B0 -> B1 -> B0 -> B1
  sage_fused<16, true><<<2048, 256, 0, stream>>>(B0, rowptr, esorted, inv, s0Wl, s0bl, s0Wr, 13, B1);
  sage_fused<64, true><<<2048, 256, 0, stream>>>(B1, rowptr, esorted, inv, s1Wl, s1bl, s1Wr, 64, B0);
  sage_fused<64, false><<<2048, 256, 0, stream>>>(B0, rowptr, esorted, inv, s2Wl, s2bl, s2Wr, 64, B1);

  // pooling + MLP
  pool_kernel<<<((N_NODES + 63) / 64 * 64 + 255) / 256, 256, 0, stream>>>(B1, batch, pooled, cnt);
  mlp_kernel<<<N_GRAPHS, 64, 0, stream>>>(pooled, cnt, mW0, mb0, mW1, mb1, mW2, mb2, mW3, mb3,
                                          (float*)d_out);
}

// Round 4
// 815.565 us; speedup vs baseline: 4.2979x; 1.4917x over previous
//
#include <hip/hip_runtime.h>
#include <hip/hip_bf16.h>

#define N_NODES 100000
#define N_EDGES 1600000
#define N_GRAPHS 250

__device__ __forceinline__ void atomAddF(float* p, float v) {
  unsafeAtomicAdd(p, v);  // hardware global_atomic_add_f32
}

__device__ __forceinline__ float4 add4(float4 a, float4 b) {
  return make_float4(a.x + b.x, a.y + b.y, a.z + b.z, a.w + b.w);
}

// Build x0 [N,16]: [node_h(9) | xg[batch](4) | 0,0,0]
__global__ void concat_kernel(const float* __restrict__ nh, const float* __restrict__ xg,
                              const int* __restrict__ batch, float* __restrict__ x0) {
  int idx = blockIdx.x * blockDim.x + threadIdx.x;
  if (idx >= N_NODES * 16) return;
  int n = idx >> 4, j = idx & 15;
  float v;
  if (j < 9)       v = nh[n * 9 + j];
  else if (j < 13) v = xg[batch[n] * 4 + (j - 9)];
  else             v = 0.0f;
  x0[idx] = v;
}

// ---- CSR build: histogram -> scan -> scatter (int atomics only) ----
__global__ void hist_kernel(const int* __restrict__ dst, int* __restrict__ deg) {
  int e = blockIdx.x * blockDim.x + threadIdx.x;
  if (e < N_EDGES) atomicAdd(&deg[dst[e]], 1);
}

__global__ void inv_kernel(const int* __restrict__ deg, float* __restrict__ inv) {
  int n = blockIdx.x * blockDim.x + threadIdx.x;
  if (n < N_NODES) inv[n] = 1.0f / fmaxf((float)deg[n], 1.0f);
}

// single-block exclusive scan of deg -> rowptr (and cursor copy)
__global__ __launch_bounds__(1024) void scan_kernel(const int* __restrict__ deg,
                                                    int* __restrict__ rowptr,
                                                    int* __restrict__ cursor) {
  const int T = 1024;
  const int C = (N_NODES + T - 1) / T;  // 98
  __shared__ int part[T];
  int t = threadIdx.x;
  int lo = t * C, hi = lo + C < N_NODES ? lo + C : N_NODES;
  int s = 0;
  for (int i = lo; i < hi; ++i) s += deg[i];
  part[t] = s;
  __syncthreads();
  for (int off = 1; off < T; off <<= 1) {  // Hillis-Steele inclusive
    int add = (t >= off) ? part[t - off] : 0;
    __syncthreads();
    part[t] += add;
    __syncthreads();
  }
  int pre = (t == 0) ? 0 : part[t - 1];
  for (int i = lo; i < hi; ++i) {
    rowptr[i] = pre; cursor[i] = pre;
    pre += deg[i];
  }
  if (t == T - 1) rowptr[N_NODES] = N_EDGES;
}

__global__ void scatter_kernel(const int* __restrict__ src, const int* __restrict__ dst,
                               int* __restrict__ cursor, int* __restrict__ esorted) {
  int e = blockIdx.x * blockDim.x + threadIdx.x;
  if (e < N_EDGES) {
    int pos = atomicAdd(&cursor[dst[e]], 1);
    esorted[pos] = src[e];
  }
}

// ---- fused gather-mean-aggregate + SAGE transform ----
// block = 256 = 4 waves; tile = 16 nodes (4 per wave, 1 per quarter-wave).
// stage1: quarter-wave gathers its node's row set via float4 lanes (16 lanes x 16B = row),
//         edge loop unrolled x4 with independent accumulators -> 16 rows in flight/wave.
// stage2: wave transforms its 4 nodes together; W in LDS (transposed, conflict-free fill),
//         as/xs rows read as LDS broadcasts.
template <int F, bool RELU>
__launch_bounds__(256)
__global__ void sage_fused(const float* __restrict__ x, const int* __restrict__ rowptr,
                           const int* __restrict__ esorted, const float* __restrict__ inv,
                           const float* __restrict__ Wl, const float* __restrict__ bl,
                           const float* __restrict__ Wr, int Fw, float* __restrict__ out) {
  constexpr int ST = (F == 64) ? 68 : 20;  // padded row stride (floats), 16B-aligned
  __shared__ float Wlt[F * 64];
  __shared__ float Wrt[F * 64];
  __shared__ float asld[16 * ST];
  __shared__ float xsld[16 * ST];
  for (int i = threadIdx.x; i < 64 * F; i += 256) {
    int h = i & 63, f = i >> 6;  // consecutive lanes -> consecutive LDS words (no conflict)
    Wlt[f * 64 + h] = (f < Fw) ? Wl[h * Fw + f] : 0.0f;
    Wrt[f * 64 + h] = (f < Fw) ? Wr[h * Fw + f] : 0.0f;
  }
  __syncthreads();
  const int lane = threadIdx.x & 63;
  const int w = threadIdx.x >> 6;
  const int q = lane >> 4;   // quarter-wave id: node within wave
  const int c = lane & 15;   // float4 column
  const float blv = bl[lane];
  const float4* xf4 = (const float4*)x;
  const int ntiles = N_NODES / 16;  // 6250
  for (int tile = blockIdx.x; tile < ntiles; tile += gridDim.x) {
    const int n = tile * 16 + w * 4 + q;
    const int e0 = rowptr[n], e1 = rowptr[n + 1];
    const float invn = inv[n];
    if (F == 64) {
      float4 a0 = {0, 0, 0, 0}, a1 = a0, a2 = a0, a3 = a0;
      int e = e0;
      for (; e + 4 <= e1; e += 4) {
        int s0 = esorted[e], s1 = esorted[e + 1], s2 = esorted[e + 2], s3 = esorted[e + 3];
        a0 = add4(a0, xf4[(size_t)s0 * 16 + c]);
        a1 = add4(a1, xf4[(size_t)s1 * 16 + c]);
        a2 = add4(a2, xf4[(size_t)s2 * 16 + c]);
        a3 = add4(a3, xf4[(size_t)s3 * 16 + c]);
      }
      for (; e < e1; ++e) a0 = add4(a0, xf4[(size_t)esorted[e] * 16 + c]);
      a0 = add4(add4(a0, a1), add4(a2, a3));
      float4 xv = xf4[(size_t)n * 16 + c];
      a0.x *= invn; a0.y *= invn; a0.z *= invn; a0.w *= invn;
      *(float4*)&asld[(w * 4 + q) * ST + 4 * c] = a0;
      *(float4*)&xsld[(w * 4 + q) * ST + 4 * c] = xv;
    } else {  // F == 16: 4 edge-subgroups x 4 float4-lanes per row
      const int eg = c >> 2, cc = c & 3;
      float4 a0 = {0, 0, 0, 0};
      for (int e = e0 + eg; e < e1; e += 4)
        a0 = add4(a0, xf4[(size_t)esorted[e] * 4 + cc]);
      a0.x += __shfl_xor(a0.x, 4); a0.y += __shfl_xor(a0.y, 4);
      a0.z += __shfl_xor(a0.z, 4); a0.w += __shfl_xor(a0.w, 4);
      a0.x += __shfl_xor(a0.x, 8); a0.y += __shfl_xor(a0.y, 8);
      a0.z += __shfl_xor(a0.z, 8); a0.w += __shfl_xor(a0.w, 8);
      if (eg == 0) {
        float4 xv = xf4[(size_t)n * 4 + cc];
        a0.x *= invn; a0.y *= invn; a0.z *= invn; a0.w *= invn;
        *(float4*)&asld[(w * 4 + q) * ST + 4 * cc] = a0;
        *(float4*)&xsld[(w * 4 + q) * ST + 4 * cc] = xv;
      }
    }
    // wave-local LDS produce->consume (wave w only touches rows w*4..w*4+3)
    __builtin_amdgcn_wave_barrier();
    const float* ar0 = &asld[(w * 4 + 0) * ST];
    const float* ar1 = &asld[(w * 4 + 1) * ST];
    const float* ar2 = &asld[(w * 4 + 2) * ST];
    const float* ar3 = &asld[(w * 4 + 3) * ST];
    const float* xr0 = &xsld[(w * 4 + 0) * ST];
    const float* xr1 = &xsld[(w * 4 + 1) * ST];
    const float* xr2 = &xsld[(w * 4 + 2) * ST];
    const float* xr3 = &xsld[(w * 4 + 3) * ST];
    float o0 = blv, o1 = blv, o2 = blv, o3 = blv;
#pragma unroll
    for (int f = 0; f < F; ++f) {
      float wl = Wlt[f * 64 + lane];
      float wr = Wrt[f * 64 + lane];
      o0 = fmaf(ar0[f], wl, fmaf(xr0[f], wr, o0));
      o1 = fmaf(ar1[f], wl, fmaf(xr1[f], wr, o1));
      o2 = fmaf(ar2[f], wl, fmaf(xr2[f], wr, o2));
      o3 = fmaf(ar3[f], wl, fmaf(xr3[f], wr, o3));
    }
    if (RELU) {
      o0 = fmaxf(o0, 0.0f); o1 = fmaxf(o1, 0.0f);
      o2 = fmaxf(o2, 0.0f); o3 = fmaxf(o3, 0.0f);
    }
    const size_t nb = (size_t)(tile * 16 + w * 4) * 64;
    out[nb + lane]       = o0;
    out[nb + 64 + lane]  = o1;
    out[nb + 128 + lane] = o2;
    out[nb + 192 + lane] = o3;
    __builtin_amdgcn_wave_barrier();
  }
}

// scatter-mean pooling: batch_idx sorted -> run-detection, one atomic per run per wave
__global__ void pool_kernel(const float* __restrict__ x, const int* __restrict__ batch,
                            float* __restrict__ pooled, float* __restrict__ cnt) {
  int wave = (blockIdx.x * blockDim.x + threadIdx.x) >> 6;
  int lane = threadIdx.x & 63;
  int n0 = wave * 64;
  if (n0 >= N_NODES) return;
  int nend = n0 + 64 < N_NODES ? n0 + 64 : N_NODES;
  int cur = -1;
  float acc = 0.0f, run = 0.0f;
  for (int n = n0; n < nend; ++n) {
    int b = batch[n];  // wave-uniform
    float v = x[(size_t)n * 64 + lane];
    if (b != cur) {
      if (cur >= 0) {
        atomAddF(&pooled[cur * 64 + lane], acc);
        if (lane == 0) atomAddF(&cnt[cur], run);
      }
      cur = b; acc = v; run = 1.0f;
    } else {
      acc += v; run += 1.0f;
    }
  }
  if (cur >= 0) {
    atomAddF(&pooled[cur * 64 + lane], acc);
    if (lane == 0) atomAddF(&cnt[cur], run);
  }
}

// per-graph MLP 64->64->64->64->1; one 64-thread block per graph
__global__ void mlp_kernel(const float* __restrict__ pooled, const float* __restrict__ cnt,
                           const float* __restrict__ W0, const float* __restrict__ b0,
                           const float* __restrict__ W1, const float* __restrict__ b1,
                           const float* __restrict__ W2, const float* __restrict__ b2,
                           const float* __restrict__ W3, const float* __restrict__ b3,
                           float* __restrict__ out) {
  int g = blockIdx.x, t = threadIdx.x;
  __shared__ float buf[2][64];
  float ic = 1.0f / fmaxf(cnt[g], 1.0f);
  buf[0][t] = pooled[g * 64 + t] * ic;
  __syncthreads();
  const float* Ws[3] = {W0, W1, W2};
  const float* Bs[3] = {b0, b1, b2};
  int cur = 0;
  for (int L = 0; L < 3; ++L) {
    const float* W = Ws[L];
    float acc = Bs[L][t];
#pragma unroll
    for (int f = 0; f < 64; ++f) acc = fmaf(W[t * 64 + f], buf[cur][f], acc);
    buf[cur ^ 1][t] = fmaxf(acc, 0.0f);
    __syncthreads();
    cur ^= 1;
  }
  float v = W3[t] * buf[cur][t];
  for (int off = 32; off; off >>= 1) v += __shfl_down(v, off);
  if (t == 0) out[g] = v + b3[0];
}

extern "C" void kernel_launch(void* const* d_in, const int* in_sizes, int n_in,
                              void* d_out, int out_size, void* d_ws, size_t ws_size,
                              hipStream_t stream) {
  const float* nh    = (const float*)d_in[0];
  const float* xg    = (const float*)d_in[1];
  const int*   ei    = (const int*)d_in[2];
  const int*   batch = (const int*)d_in[3];
  const float* s0Wl  = (const float*)d_in[4];
  const float* s0bl  = (const float*)d_in[5];
  const float* s0Wr  = (const float*)d_in[6];
  const float* s1Wl  = (const float*)d_in[7];
  const float* s1bl  = (const float*)d_in[8];
  const float* s1Wr  = (const float*)d_in[9];
  const float* s2Wl  = (const float*)d_in[10];
  const float* s2bl  = (const float*)d_in[11];
  const float* s2Wr  = (const float*)d_in[12];
  const float* mW0   = (const float*)d_in[13];
  const float* mb0   = (const float*)d_in[14];
  const float* mW1   = (const float*)d_in[15];
  const float* mb1   = (const float*)d_in[16];
  const float* mW2   = (const float*)d_in[17];
  const float* mb2   = (const float*)d_in[18];
  const float* mW3   = (const float*)d_in[19];
  const float* mb3   = (const float*)d_in[20];

  const int* src = ei;
  const int* dst = ei + N_EDGES;

  // ws layout
  float* B0     = (float*)d_ws;                     // N*64
  float* B1     = B0 + (size_t)N_NODES * 64;        // N*64
  float* inv    = B1 + (size_t)N_NODES * 64;        // N
  float* pooled = inv + N_NODES;                    // 250*64
  float* cnt    = pooled + (size_t)N_GRAPHS * 64;   // 250
  int*   deg     = (int*)(cnt + N_GRAPHS);          // N
  int*   rowptr  = deg + N_NODES;                   // N+1
  int*   cursor  = rowptr + (N_NODES + 1);          // N
  int*   esorted = cursor + N_NODES;                // E

  hipMemsetAsync(deg, 0, N_NODES * sizeof(int), stream);
  hipMemsetAsync(pooled, 0, (N_GRAPHS * 64 + N_GRAPHS) * sizeof(float), stream);

  // CSR build
  hist_kernel<<<(N_EDGES + 255) / 256, 256, 0, stream>>>(dst, deg);
  inv_kernel<<<(N_NODES + 255) / 256, 256, 0, stream>>>(deg, inv);
  scan_kernel<<<1, 1024, 0, stream>>>(deg, rowptr, cursor);
  scatter_kernel<<<(N_EDGES + 255) / 256, 256, 0, stream>>>(src, dst, cursor, esorted);

  // x0 (stride 16) into B0
  concat_kernel<<<(N_NODES * 16 + 255) / 256, 256, 0, stream>>>(nh, xg, batch, B0);

  // fused layers: B0 -> B1 -> B0 -> B1
  sage_fused<16, true><<<2048, 256, 0, stream>>>(B0, rowptr, esorted, inv, s0Wl, s0bl, s0Wr, 13, B1);
  sage_fused<64, true><<<2048, 256, 0, stream>>>(B1, rowptr, esorted, inv, s1Wl, s1bl, s1Wr, 64, B0);
  sage_fused<64, false><<<2048, 256, 0, stream>>>(B0, rowptr, esorted, inv, s2Wl, s2bl, s2Wr, 64, B1);

  // pooling + MLP
  pool_kernel<<<((N_NODES + 63) / 64 * 64 + 255) / 256, 256, 0, stream>>>(B1, batch, pooled, cnt);
  mlp_kernel<<<N_GRAPHS, 64, 0, stream>>>(pooled, cnt, mW0, mb0, mW1, mb1, mW2, mb2, mW3, mb3,
                                          (float*)d_out);
}

// Round 5
// 600.067 us; speedup vs baseline: 5.8414x; 1.3591x over previous
//
#include <hip/hip_runtime.h>
#include <hip/hip_bf16.h>

#define N_NODES 100000
#define N_EDGES 1600000
#define N_GRAPHS 250
#define SCAN_CHUNK 512
#define NCHUNKS ((N_NODES + SCAN_CHUNK - 1) / SCAN_CHUNK)  // 196

__device__ __forceinline__ void atomAddF(float* p, float v) {
  unsafeAtomicAdd(p, v);  // hardware global_atomic_add_f32
}

__device__ __forceinline__ float4 add4(float4 a, float4 b) {
  return make_float4(a.x + b.x, a.y + b.y, a.z + b.z, a.w + b.w);
}

// Build x0 [N,16]: [node_h(9) | xg[batch](4) | 0,0,0]
__global__ void concat_kernel(const float* __restrict__ nh, const float* __restrict__ xg,
                              const int* __restrict__ batch, float* __restrict__ x0) {
  int idx = blockIdx.x * blockDim.x + threadIdx.x;
  if (idx >= N_NODES * 16) return;
  int n = idx >> 4, j = idx & 15;
  float v;
  if (j < 9)       v = nh[n * 9 + j];
  else if (j < 13) v = xg[batch[n] * 4 + (j - 9)];
  else             v = 0.0f;
  x0[idx] = v;
}

// ---- CSR build: histogram -> hierarchical scan -> scatter (int atomics only) ----
__global__ void hist_kernel(const int* __restrict__ dst, int* __restrict__ deg) {
  int e = blockIdx.x * blockDim.x + threadIdx.x;
  if (e < N_EDGES) atomicAdd(&deg[dst[e]], 1);
}

// A: per-chunk partial sums (196 blocks x 256 threads, 2 elems/thread)
__global__ __launch_bounds__(256) void partial_kernel(const int* __restrict__ deg,
                                                      int* __restrict__ partial) {
  int b = blockIdx.x, t = threadIdx.x;
  int i0 = b * SCAN_CHUNK + t * 2;
  int s = 0;
  if (i0 < N_NODES) s += deg[i0];
  if (i0 + 1 < N_NODES) s += deg[i0 + 1];
  for (int off = 1; off < 64; off <<= 1) s += __shfl_xor(s, off);
  __shared__ int wsum[4];
  if ((t & 63) == 0) wsum[t >> 6] = s;
  __syncthreads();
  if (t == 0) partial[b] = wsum[0] + wsum[1] + wsum[2] + wsum[3];
}

// B: scan the 196 chunk partials (1 tiny block)
__global__ __launch_bounds__(256) void chunkscan_kernel(const int* __restrict__ partial,
                                                        int* __restrict__ chunkoff,
                                                        int* __restrict__ rowptr) {
  __shared__ int sh[256];
  int t = threadIdx.x;
  int v = (t < NCHUNKS) ? partial[t] : 0;
  sh[t] = v;
  __syncthreads();
  for (int off = 1; off < 256; off <<= 1) {  // Hillis-Steele inclusive
    int u = (t >= off) ? sh[t - off] : 0;
    __syncthreads();
    sh[t] += u;
    __syncthreads();
  }
  if (t < NCHUNKS) chunkoff[t] = sh[t] - v;  // exclusive prefix
  if (t == 0) rowptr[N_NODES] = N_EDGES;
}

// C: in-chunk scan + chunk offset -> rowptr/cursor; also emits inv = 1/max(deg,1)
__global__ __launch_bounds__(256) void rowptr_kernel(const int* __restrict__ deg,
                                                     const int* __restrict__ chunkoff,
                                                     int* __restrict__ rowptr,
                                                     int* __restrict__ cursor,
                                                     float* __restrict__ inv) {
  int b = blockIdx.x, t = threadIdx.x;
  int lane = t & 63, w = t >> 6;
  int i0 = b * SCAN_CHUNK + t * 2;
  int d0 = (i0 < N_NODES) ? deg[i0] : 0;
  int d1 = (i0 + 1 < N_NODES) ? deg[i0 + 1] : 0;
  int ps = d0 + d1;
  int v = ps;
  for (int off = 1; off < 64; off <<= 1) {  // wave-inclusive scan
    int u = __shfl_up(v, off);
    if (lane >= off) v += u;
  }
  __shared__ int wtot[4];
  if (lane == 63) wtot[w] = v;
  __syncthreads();
  int woff = 0;
  for (int i = 0; i < w; ++i) woff += wtot[i];
  int excl = chunkoff[b] + woff + v - ps;
  if (i0 < N_NODES) {
    rowptr[i0] = excl; cursor[i0] = excl;
    inv[i0] = 1.0f / fmaxf((float)d0, 1.0f);
  }
  if (i0 + 1 < N_NODES) {
    rowptr[i0 + 1] = excl + d0; cursor[i0 + 1] = excl + d0;
    inv[i0 + 1] = 1.0f / fmaxf((float)d1, 1.0f);
  }
}

__global__ void scatter_kernel(const int* __restrict__ src, const int* __restrict__ dst,
                               int* __restrict__ cursor, int* __restrict__ esorted) {
  int e = blockIdx.x * blockDim.x + threadIdx.x;
  if (e < N_EDGES) {
    int pos = atomicAdd(&cursor[dst[e]], 1);
    esorted[pos] = src[e];
  }
}

// ---- fused gather-mean-aggregate + SAGE transform ----
// block = 256 = 4 waves; tile = 16 nodes (4 per wave, 1 per quarter-wave).
// stage1: quarter-wave gathers its node's row set via float4 lanes (16 lanes x 16B = row),
//         edge loop unrolled x4 with independent accumulators -> 16 rows in flight/wave.
// stage2: wave transforms its 4 nodes together; W in LDS (transposed, conflict-free fill),
//         as/xs rows read as LDS broadcasts.
template <int F, bool RELU>
__launch_bounds__(256)
__global__ void sage_fused(const float* __restrict__ x, const int* __restrict__ rowptr,
                           const int* __restrict__ esorted, const float* __restrict__ inv,
                           const float* __restrict__ Wl, const float* __restrict__ bl,
                           const float* __restrict__ Wr, int Fw, float* __restrict__ out) {
  constexpr int ST = (F == 64) ? 68 : 20;  // padded row stride (floats), 16B-aligned
  __shared__ float Wlt[F * 64];
  __shared__ float Wrt[F * 64];
  __shared__ float asld[16 * ST];
  __shared__ float xsld[16 * ST];
  for (int i = threadIdx.x; i < 64 * F; i += 256) {
    int h = i & 63, f = i >> 6;  // consecutive lanes -> consecutive LDS words (no conflict)
    Wlt[f * 64 + h] = (f < Fw) ? Wl[h * Fw + f] : 0.0f;
    Wrt[f * 64 + h] = (f < Fw) ? Wr[h * Fw + f] : 0.0f;
  }
  __syncthreads();
  const int lane = threadIdx.x & 63;
  const int w = threadIdx.x >> 6;
  const int q = lane >> 4;   // quarter-wave id: node within wave
  const int c = lane & 15;   // float4 column
  const float blv = bl[lane];
  const float4* xf4 = (const float4*)x;
  const int ntiles = N_NODES / 16;  // 6250
  for (int tile = blockIdx.x; tile < ntiles; tile += gridDim.x) {
    const int n = tile * 16 + w * 4 + q;
    const int e0 = rowptr[n], e1 = rowptr[n + 1];
    const float invn = inv[n];
    if (F == 64) {
      float4 a0 = {0, 0, 0, 0}, a1 = a0, a2 = a0, a3 = a0;
      int e = e0;
      for (; e + 4 <= e1; e += 4) {
        int s0 = esorted[e], s1 = esorted[e + 1], s2 = esorted[e + 2], s3 = esorted[e + 3];
        a0 = add4(a0, xf4[(size_t)s0 * 16 + c]);
        a1 = add4(a1, xf4[(size_t)s1 * 16 + c]);
        a2 = add4(a2, xf4[(size_t)s2 * 16 + c]);
        a3 = add4(a3, xf4[(size_t)s3 * 16 + c]);
      }
      for (; e < e1; ++e) a0 = add4(a0, xf4[(size_t)esorted[e] * 16 + c]);
      a0 = add4(add4(a0, a1), add4(a2, a3));
      float4 xv = xf4[(size_t)n * 16 + c];
      a0.x *= invn; a0.y *= invn; a0.z *= invn; a0.w *= invn;
      *(float4*)&asld[(w * 4 + q) * ST + 4 * c] = a0;
      *(float4*)&xsld[(w * 4 + q) * ST + 4 * c] = xv;
    } else {  // F == 16: 4 edge-subgroups x 4 float4-lanes per row
      const int eg = c >> 2, cc = c & 3;
      float4 a0 = {0, 0, 0, 0};
      for (int e = e0 + eg; e < e1; e += 4)
        a0 = add4(a0, xf4[(size_t)esorted[e] * 4 + cc]);
      a0.x += __shfl_xor(a0.x, 4); a0.y += __shfl_xor(a0.y, 4);
      a0.z += __shfl_xor(a0.z, 4); a0.w += __shfl_xor(a0.w, 4);
      a0.x += __shfl_xor(a0.x, 8); a0.y += __shfl_xor(a0.y, 8);
      a0.z += __shfl_xor(a0.z, 8); a0.w += __shfl_xor(a0.w, 8);
      if (eg == 0) {
        float4 xv = xf4[(size_t)n * 4 + cc];
        a0.x *= invn; a0.y *= invn; a0.z *= invn; a0.w *= invn;
        *(float4*)&asld[(w * 4 + q) * ST + 4 * cc] = a0;
        *(float4*)&xsld[(w * 4 + q) * ST + 4 * cc] = xv;
      }
    }
    // wave-local LDS produce->consume (wave w only touches rows w*4..w*4+3)
    __builtin_amdgcn_wave_barrier();
    const float* ar0 = &asld[(w * 4 + 0) * ST];
    const float* ar1 = &asld[(w * 4 + 1) * ST];
    const float* ar2 = &asld[(w * 4 + 2) * ST];
    const float* ar3 = &asld[(w * 4 + 3) * ST];
    const float* xr0 = &xsld[(w * 4 + 0) * ST];
    const float* xr1 = &xsld[(w * 4 + 1) * ST];
    const float* xr2 = &xsld[(w * 4 + 2) * ST];
    const float* xr3 = &xsld[(w * 4 + 3) * ST];
    float o0 = blv, o1 = blv, o2 = blv, o3 = blv;
#pragma unroll
    for (int f = 0; f < F; ++f) {
      float wl = Wlt[f * 64 + lane];
      float wr = Wrt[f * 64 + lane];
      o0 = fmaf(ar0[f], wl, fmaf(xr0[f], wr, o0));
      o1 = fmaf(ar1[f], wl, fmaf(xr1[f], wr, o1));
      o2 = fmaf(ar2[f], wl, fmaf(xr2[f], wr, o2));
      o3 = fmaf(ar3[f], wl, fmaf(xr3[f], wr, o3));
    }
    if (RELU) {
      o0 = fmaxf(o0, 0.0f); o1 = fmaxf(o1, 0.0f);
      o2 = fmaxf(o2, 0.0f); o3 = fmaxf(o3, 0.0f);
    }
    const size_t nb = (size_t)(tile * 16 + w * 4) * 64;
    out[nb + lane]       = o0;
    out[nb + 64 + lane]  = o1;
    out[nb + 128 + lane] = o2;
    out[nb + 192 + lane] = o3;
    __builtin_amdgcn_wave_barrier();
  }
}

// scatter-mean pooling: batch_idx sorted -> run-detection, one atomic per run per wave
__global__ void pool_kernel(const float* __restrict__ x, const int* __restrict__ batch,
                            float* __restrict__ pooled, float* __restrict__ cnt) {
  int wave = (blockIdx.x * blockDim.x + threadIdx.x) >> 6;
  int lane = threadIdx.x & 63;
  int n0 = wave * 64;
  if (n0 >= N_NODES) return;
  int nend = n0 + 64 < N_NODES ? n0 + 64 : N_NODES;
  int cur = -1;
  float acc = 0.0f, run = 0.0f;
  for (int n = n0; n < nend; ++n) {
    int b = batch[n];  // wave-uniform
    float v = x[(size_t)n * 64 + lane];
    if (b != cur) {
      if (cur >= 0) {
        atomAddF(&pooled[cur * 64 + lane], acc);
        if (lane == 0) atomAddF(&cnt[cur], run);
      }
      cur = b; acc = v; run = 1.0f;
    } else {
      acc += v; run += 1.0f;
    }
  }
  if (cur >= 0) {
    atomAddF(&pooled[cur * 64 + lane], acc);
    if (lane == 0) atomAddF(&cnt[cur], run);
  }
}

// per-graph MLP 64->64->64->64->1; one 64-thread block per graph
__global__ void mlp_kernel(const float* __restrict__ pooled, const float* __restrict__ cnt,
                           const float* __restrict__ W0, const float* __restrict__ b0,
                           const float* __restrict__ W1, const float* __restrict__ b1,
                           const float* __restrict__ W2, const float* __restrict__ b2,
                           const float* __restrict__ W3, const float* __restrict__ b3,
                           float* __restrict__ out) {
  int g = blockIdx.x, t = threadIdx.x;
  __shared__ float buf[2][64];
  float ic = 1.0f / fmaxf(cnt[g], 1.0f);
  buf[0][t] = pooled[g * 64 + t] * ic;
  __syncthreads();
  const float* Ws[3] = {W0, W1, W2};
  const float* Bs[3] = {b0, b1, b2};
  int cur = 0;
  for (int L = 0; L < 3; ++L) {
    const float* W = Ws[L];
    float acc = Bs[L][t];
#pragma unroll
    for (int f = 0; f < 64; ++f) acc = fmaf(W[t * 64 + f], buf[cur][f], acc);
    buf[cur ^ 1][t] = fmaxf(acc, 0.0f);
    __syncthreads();
    cur ^= 1;
  }
  float v = W3[t] * buf[cur][t];
  for (int off = 32; off; off >>= 1) v += __shfl_down(v, off);
  if (t == 0) out[g] = v + b3[0];
}

extern "C" void kernel_launch(void* const* d_in, const int* in_sizes, int n_in,
                              void* d_out, int out_size, void* d_ws, size_t ws_size,
                              hipStream_t stream) {
  const float* nh    = (const float*)d_in[0];
  const float* xg    = (const float*)d_in[1];
  const int*   ei    = (const int*)d_in[2];
  const int*   batch = (const int*)d_in[3];
  const float* s0Wl  = (const float*)d_in[4];
  const float* s0bl  = (const float*)d_in[5];
  const float* s0Wr  = (const float*)d_in[6];
  const float* s1Wl  = (const float*)d_in[7];
  const float* s1bl  = (const float*)d_in[8];
  const float* s1Wr  = (const float*)d_in[9];
  const float* s2Wl  = (const float*)d_in[10];
  const float* s2bl  = (const float*)d_in[11];
  const float* s2Wr  = (const float*)d_in[12];
  const float* mW0   = (const float*)d_in[13];
  const float* mb0   = (const float*)d_in[14];
  const float* mW1   = (const float*)d_in[15];
  const float* mb1   = (const float*)d_in[16];
  const float* mW2   = (const float*)d_in[17];
  const float* mb2   = (const float*)d_in[18];
  const float* mW3   = (const float*)d_in[19];
  const float* mb3   = (const float*)d_in[20];

  const int* src = ei;
  const int* dst = ei + N_EDGES;

  // ws layout
  float* B0     = (float*)d_ws;                     // N*64
  float* B1     = B0 + (size_t)N_NODES * 64;        // N*64
  float* inv    = B1 + (size_t)N_NODES * 64;        // N
  float* pooled = inv + N_NODES;                    // 250*64
  float* cnt    = pooled + (size_t)N_GRAPHS * 64;   // 250
  int*   deg     = (int*)(cnt + N_GRAPHS);          // N
  int*   rowptr  = deg + N_NODES;                   // N+1
  int*   cursor  = rowptr + (N_NODES + 1);          // N
  int*   esorted = cursor + N_NODES;                // E
  int*   partial  = esorted + N_EDGES;              // 256
  int*   chunkoff = partial + 256;                  // 256

  hipMemsetAsync(deg, 0, N_NODES * sizeof(int), stream);
  hipMemsetAsync(pooled, 0, (N_GRAPHS * 64 + N_GRAPHS) * sizeof(float), stream);

  // CSR build (hierarchical scan)
  hist_kernel<<<(N_EDGES + 255) / 256, 256, 0, stream>>>(dst, deg);
  partial_kernel<<<NCHUNKS, 256, 0, stream>>>(deg, partial);
  chunkscan_kernel<<<1, 256, 0, stream>>>(partial, chunkoff, rowptr);
  rowptr_kernel<<<NCHUNKS, 256, 0, stream>>>(deg, chunkoff, rowptr, cursor, inv);
  scatter_kernel<<<(N_EDGES + 255) / 256, 256, 0, stream>>>(src, dst, cursor, esorted);

  // x0 (stride 16) into B0
  concat_kernel<<<(N_NODES * 16 + 255) / 256, 256, 0, stream>>>(nh, xg, batch, B0);

  // fused layers: B0 -> B1 -> B0 -> B1
  sage_fused<16, true><<<2048, 256, 0, stream>>>(B0, rowptr, esorted, inv, s0Wl, s0bl, s0Wr, 13, B1);
  sage_fused<64, true><<<2048, 256, 0, stream>>>(B1, rowptr, esorted, inv, s1Wl, s1bl, s1Wr, 64, B0);
  sage_fused<64, false><<<2048, 256, 0, stream>>>(B0, rowptr, esorted, inv, s2Wl, s2bl, s2Wr, 64, B1);

  // pooling + MLP
  pool_kernel<<<((N_NODES + 63) / 64 * 64 + 255) / 256, 256, 0, stream>>>(B1, batch, pooled, cnt);
  mlp_kernel<<<N_GRAPHS, 64, 0, stream>>>(pooled, cnt, mW0, mb0, mW1, mb1, mW2, mb2, mW3, mb3,
                                          (float*)d_out);
}